// Round 1
// baseline (1117.358 us; speedup 1.0000x reference)
//
#include <hip/hip_runtime.h>

#define NB 64
#define NS 2048
#define ND 64

typedef __bf16 bf16x8 __attribute__((ext_vector_type(8)));
typedef float f32x4 __attribute__((ext_vector_type(4)));

__device__ __forceinline__ unsigned short f2bs(float x) {
  __bf16 h = (__bf16)x;
  return __builtin_bit_cast(unsigned short, h);
}

__device__ __forceinline__ bf16x8 cvt8(f32x4 a, f32x4 b) {
  bf16x8 r;
  r[0] = (__bf16)a[0]; r[1] = (__bf16)a[1]; r[2] = (__bf16)a[2]; r[3] = (__bf16)a[3];
  r[4] = (__bf16)b[0]; r[5] = (__bf16)b[1]; r[6] = (__bf16)b[2]; r[7] = (__bf16)b[3];
  return r;
}

__device__ __forceinline__ bf16x8 load_cvt8(const float* p) {
  f32x4 a = *reinterpret_cast<const f32x4*>(p);
  f32x4 b = *reinterpret_cast<const f32x4*>(p + 4);
  return cvt8(a, b);
}

// Layout facts used (gfx950 mfma_f32_16x16x32_bf16):
//  - C/D: D[m][n], n = lane&15, m = 4*(lane>>4) + reg   [HW-verified]
//  - A/B k-slots: any k<->(group,slot) bijection is valid as long as A and B
//    use the SAME ordering (dot product is permutation-invariant). We use
//    k = 8*(lane>>4) + slot, i.e. contiguous 8-element (16B) loads.
__global__ __launch_bounds__(256) void DotProductAttention_22436909154804_kernel(
    const float* __restrict__ Q, const float* __restrict__ K,
    const float* __restrict__ V, const int* __restrict__ M,
    float* __restrict__ ctx, float* __restrict__ wts) {
  __shared__ __attribute__((aligned(16))) unsigned short Vt[64][40];     // V^T tile [d][kk], bf16, pad->40
  __shared__ __attribute__((aligned(16))) unsigned short Wl[4][16][40];  // per-wave W tile [q][kk], bf16

  const int tid  = threadIdx.x;
  const int w    = tid >> 6;     // wave 0..3
  const int lane = tid & 63;
  const int g    = lane >> 4;    // 0..3
  const int c    = lane & 15;    // 0..15

  const int b  = blockIdx.x >> 5;   // batch
  const int qt = blockIdx.x & 31;   // q-tile of 64
  const int q0 = qt * 64 + w * 16;  // this wave's first q row

  const size_t bq = (size_t)b * NS;

  // Q fragments for 16 q-rows, d split 0..31 / 32..63
  const float* qp = Q + (bq + q0 + c) * ND + 8 * g;
  const bf16x8 qf0 = load_cvt8(qp);
  const bf16x8 qf1 = load_cvt8(qp + 32);

  const float* Kb = K + bq * ND;

  // score subtiles: subtile-lo covers even k (k0+2c), subtile-hi odd (k0+2c+1)
  auto scores = [&](int k0, f32x4& clo, f32x4& chi) {
    const float* kr = Kb + (size_t)(k0 + 2 * c) * ND + 8 * g;
    bf16x8 k00 = load_cvt8(kr);
    bf16x8 k01 = load_cvt8(kr + 32);
    bf16x8 k10 = load_cvt8(kr + ND);
    bf16x8 k11 = load_cvt8(kr + ND + 32);
    f32x4 z = {0.f, 0.f, 0.f, 0.f};
    clo = __builtin_amdgcn_mfma_f32_16x16x32_bf16(qf0, k00, z, 0, 0, 0);
    clo = __builtin_amdgcn_mfma_f32_16x16x32_bf16(qf1, k01, clo, 0, 0, 0);
    chi = __builtin_amdgcn_mfma_f32_16x16x32_bf16(qf0, k10, z, 0, 0, 0);
    chi = __builtin_amdgcn_mfma_f32_16x16x32_bf16(qf1, k11, chi, 0, 0, 0);
  };

  // ---------------- Phase 1: row sums of exp(masked scores) ----------------
  float rs[4] = {0.f, 0.f, 0.f, 0.f};
  for (int k0 = 0; k0 < NS; k0 += 32) {
    f32x4 clo, chi;
    scores(k0, clo, chi);
#pragma unroll
    for (int r = 0; r < 4; ++r) {
      const int2 mm = *reinterpret_cast<const int2*>(M + (size_t)(q0 + 4 * g + r) * NS + k0 + 2 * c);
      float pl = mm.x ? __expf(clo[r] * 0.125f) : 0.f;
      float ph = mm.y ? __expf(chi[r] * 0.125f) : 0.f;
      rs[r] += pl + ph;
    }
  }
  float inv[4];
#pragma unroll
  for (int r = 0; r < 4; ++r) {
    float s = rs[r];
    s += __shfl_xor(s, 1);
    s += __shfl_xor(s, 2);
    s += __shfl_xor(s, 4);
    s += __shfl_xor(s, 8);
    inv[r] = 1.f / s;
  }

  // ---------------- Phase 2: weights out + PV ----------------
  const int p  = tid >> 4;        // 0..15 (row pair for V staging)
  const int d0 = (tid & 15) * 4;  // 0..60
  const float* Vb = V + bq * ND;

  f32x4 acc[4] = {};  // context acc, 4 d-tiles of 16

  for (int k0 = 0; k0 < NS; k0 += 32) {
    // cooperative V tile load (regs): rows k0+2p, k0+2p+1, cols d0..d0+3
    const float* vr = Vb + (size_t)(k0 + 2 * p) * ND + d0;
    f32x4 v0 = *reinterpret_cast<const f32x4*>(vr);
    f32x4 v1 = *reinterpret_cast<const f32x4*>(vr + ND);
    unsigned int vpk[4];
#pragma unroll
    for (int j = 0; j < 4; ++j)
      vpk[j] = (unsigned int)f2bs(v0[j]) | ((unsigned int)f2bs(v1[j]) << 16);

    f32x4 clo, chi;
    scores(k0, clo, chi);

    unsigned int wpk[4];
#pragma unroll
    for (int r = 0; r < 4; ++r) {
      const int2 mm = *reinterpret_cast<const int2*>(M + (size_t)(q0 + 4 * g + r) * NS + k0 + 2 * c);
      float wl = mm.x ? __expf(clo[r] * 0.125f) * inv[r] : 0.f;
      float wh = mm.y ? __expf(chi[r] * 0.125f) * inv[r] : 0.f;
      float2 st;
      st.x = wl; st.y = wh;
      *reinterpret_cast<float2*>(wts + (bq + q0 + 4 * g + r) * NS + k0 + 2 * c) = st;
      wpk[r] = (unsigned int)f2bs(wl) | ((unsigned int)f2bs(wh) << 16);
    }

    __syncthreads();  // previous iter's PV LDS reads done before overwrite
#pragma unroll
    for (int j = 0; j < 4; ++j)
      *reinterpret_cast<unsigned int*>(&Vt[d0 + j][2 * p]) = vpk[j];
#pragma unroll
    for (int r = 0; r < 4; ++r)
      *reinterpret_cast<unsigned int*>(&Wl[w][4 * g + r][2 * c]) = wpk[r];
    __syncthreads();  // LDS tiles visible

    // PV: A = W (rows = q), B = V^T-staged (cols = d)
    bf16x8 wa = *reinterpret_cast<const bf16x8*>(&Wl[w][c][8 * g]);
#pragma unroll
    for (int dt = 0; dt < 4; ++dt) {
      bf16x8 vbf = *reinterpret_cast<const bf16x8*>(&Vt[dt * 16 + c][8 * g]);
      acc[dt] = __builtin_amdgcn_mfma_f32_16x16x32_bf16(wa, vbf, acc[dt], 0, 0, 0);
    }
  }

#pragma unroll
  for (int dt = 0; dt < 4; ++dt)
#pragma unroll
    for (int r = 0; r < 4; ++r)
      ctx[(bq + q0 + 4 * g + r) * ND + dt * 16 + c] = acc[dt][r];
}

extern "C" void kernel_launch(void* const* d_in, const int* in_sizes, int n_in,
                              void* d_out, int out_size, void* d_ws, size_t ws_size,
                              hipStream_t stream) {
  const float* Q = (const float*)d_in[0];
  const float* K = (const float*)d_in[1];
  const float* V = (const float*)d_in[2];
  const int*   M = (const int*)d_in[3];
  float* ctx = (float*)d_out;                               // [B,S,D]
  float* wts = (float*)d_out + (size_t)NB * NS * ND;        // [B,S,S]

  dim3 grid(NB * (NS / 64));
  dim3 block(256);
  hipLaunchKernelGGL(DotProductAttention_22436909154804_kernel, grid, block, 0, stream,
                     Q, K, V, M, ctx, wts);
}

// Round 2
// 685.326 us; speedup vs baseline: 1.6304x; 1.6304x over previous
//
#include <hip/hip_runtime.h>

#define NB 64
#define NS 2048
#define ND 64
#define KSTEP 64
#define NIT (NS / KSTEP)  // 32

typedef __bf16 bf16x8 __attribute__((ext_vector_type(8)));
typedef float f32x4 __attribute__((ext_vector_type(4)));
typedef unsigned int u32;
typedef u32 u32x2 __attribute__((ext_vector_type(2)));
typedef u32 u32x4 __attribute__((ext_vector_type(4)));

__device__ __forceinline__ unsigned short f2bs(float x) {
  __bf16 h = (__bf16)x;
  return __builtin_bit_cast(unsigned short, h);
}

__device__ __forceinline__ bf16x8 cvt8(f32x4 a, f32x4 b) {
  bf16x8 r;
  r[0] = (__bf16)a[0]; r[1] = (__bf16)a[1]; r[2] = (__bf16)a[2]; r[3] = (__bf16)a[3];
  r[4] = (__bf16)b[0]; r[5] = (__bf16)b[1]; r[6] = (__bf16)b[2]; r[7] = (__bf16)b[3];
  return r;
}

// MFMA 16x16x32_bf16 layout facts (HW-verified by round-1 kernel):
//   A-frag: lane holds A[row = lane&15][k = 8*(lane>>4) + s]
//   B-frag: lane holds B[k = 8*(lane>>4) + s][col = lane&15]
//   C/D   : lane holds D[m = 4*(lane>>4) + reg][n = lane&15]
// Role swap: QK^T computes D[k][q] (A=K, B=Q) so each lane owns
// W[q = c][k = 16j + 4g + r] -> float4 wts stores + direct PV B-operand.
__global__ __launch_bounds__(256, 4) void DotProductAttention_22436909154804_kernel(
    const float* __restrict__ Q, const float* __restrict__ K,
    const float* __restrict__ V, const int* __restrict__ M,
    float* __restrict__ ctx, float* __restrict__ wts) {
  // K tile: [k][d] bf16, row padded 64->72.  V tile: transposed [d][k], padded.
  __shared__ __attribute__((aligned(16))) unsigned short Kt[2][64][72];
  __shared__ __attribute__((aligned(16))) unsigned short Vt[2][64][72];

  const int tid  = threadIdx.x;
  const int lane = tid & 63;
  const int w    = tid >> 6;
  const int g    = lane >> 4;  // 0..3
  const int c    = lane & 15;  // 0..15

  // XCD-bijective swizzle: 2048 blocks, 8 XCDs -> each XCD runs 8 batches
  // sequentially (32 CUs/XCD ~ 32 q-tiles/batch) => K/V/mask L2-resident.
  const int bid = blockIdx.x;
  const int vb  = (bid & 7) * 256 + (bid >> 3);
  const int b   = vb >> 5;
  const int qt  = vb & 31;
  const int q0w = qt * 64 + w * 16;
  const size_t bq = (size_t)b * NS;

  // Q fragments (B operand): lane (g,c) <- Q[q0w+c][8g..8g+7], [32+8g..]
  const float* qp = Q + (bq + q0w + c) * ND + 8 * g;
  const bf16x8 qf0 = cvt8(*(const f32x4*)qp, *(const f32x4*)(qp + 4));
  const bf16x8 qf1 = cvt8(*(const f32x4*)(qp + 32), *(const f32x4*)(qp + 36));

  const float* Kb = K + bq * ND;
  const float* Vb = V + bq * ND;
  const int* Mrow = M + (size_t)(q0w + c) * NS;

  // staging assignments
  const int skr = tid >> 2;          // K row 0..63
  const int skd = (tid & 3) * 16;    // K col quarter
  const int svp = tid >> 4;          // V k-pair 0..15
  const int svd = (tid & 15) * 4;    // V d0

  f32x4 kst[4], vst[4];

  auto issueK = [&](int kb) {
    const float* p = Kb + (size_t)(kb + skr) * ND + skd;
    kst[0] = *(const f32x4*)p;       kst[1] = *(const f32x4*)(p + 4);
    kst[2] = *(const f32x4*)(p + 8); kst[3] = *(const f32x4*)(p + 12);
  };
  auto writeK = [&](int buf) {
    *(bf16x8*)&Kt[buf][skr][skd]     = cvt8(kst[0], kst[1]);
    *(bf16x8*)&Kt[buf][skr][skd + 8] = cvt8(kst[2], kst[3]);
  };
  auto issueV = [&](int kb) {
    const float* p = Vb + (size_t)(kb + 2 * svp) * ND + svd;
    vst[0] = *(const f32x4*)p;            vst[1] = *(const f32x4*)(p + ND);
    vst[2] = *(const f32x4*)(p + 32 * ND); vst[3] = *(const f32x4*)(p + 33 * ND);
  };
  auto writeV = [&](int buf) {
#pragma unroll
    for (int j = 0; j < 4; ++j) {
      u32 lo = (u32)f2bs(vst[0][j]) | ((u32)f2bs(vst[1][j]) << 16);
      u32 hi = (u32)f2bs(vst[2][j]) | ((u32)f2bs(vst[3][j]) << 16);
      *(u32*)&Vt[buf][svd + j][2 * svp]      = lo;  // k = 2p, 2p+1
      *(u32*)&Vt[buf][svd + j][32 + 2 * svp] = hi;  // k = 32+2p, 33+2p
    }
  };

  const f32x4 zz = {0.f, 0.f, 0.f, 0.f};

  // ---------------- Phase 1: row sums ----------------
  float rs = 0.f;
  issueK(0);
  writeK(0);
  __syncthreads();
  for (int it = 0; it < NIT; ++it) {
    const int kb  = it * KSTEP;
    const int cur = it & 1;
    if (it + 1 < NIT) issueK(kb + KSTEP);
#pragma unroll
    for (int j = 0; j < 4; ++j) {
      bf16x8 a0 = *(const bf16x8*)&Kt[cur][16 * j + c][8 * g];
      bf16x8 a1 = *(const bf16x8*)&Kt[cur][16 * j + c][32 + 8 * g];
      f32x4 s = __builtin_amdgcn_mfma_f32_16x16x32_bf16(a0, qf0, zz, 0, 0, 0);
      s = __builtin_amdgcn_mfma_f32_16x16x32_bf16(a1, qf1, s, 0, 0, 0);
      const int4 mm = *(const int4*)(Mrow + kb + 16 * j + 4 * g);
      rs += (mm.x ? __expf(s[0] * 0.125f) : 0.f)
          + (mm.y ? __expf(s[1] * 0.125f) : 0.f)
          + (mm.z ? __expf(s[2] * 0.125f) : 0.f)
          + (mm.w ? __expf(s[3] * 0.125f) : 0.f);
    }
    if (it + 1 < NIT) writeK((it + 1) & 1);
    __syncthreads();
  }
  rs += __shfl_xor(rs, 16);
  rs += __shfl_xor(rs, 32);
  const float inv = 1.f / rs;

  // ---------------- Phase 2: weights out + PV ----------------
  f32x4 acc[4] = {zz, zz, zz, zz};
  issueK(0); issueV(0);
  writeK(0); writeV(0);
  __syncthreads();
  float* wrow = wts + (bq + q0w + c) * NS;
  for (int it = 0; it < NIT; ++it) {
    const int kb  = it * KSTEP;
    const int cur = it & 1;
    if (it + 1 < NIT) { issueK(kb + KSTEP); issueV(kb + KSTEP); }

    // QK^T: D[k][q], subtile j covers k = kb+16j .. +15
    f32x4 s[4];
#pragma unroll
    for (int j = 0; j < 4; ++j) {
      bf16x8 a0 = *(const bf16x8*)&Kt[cur][16 * j + c][8 * g];
      bf16x8 a1 = *(const bf16x8*)&Kt[cur][16 * j + c][32 + 8 * g];
      s[j] = __builtin_amdgcn_mfma_f32_16x16x32_bf16(a0, qf0, zz, 0, 0, 0);
      s[j] = __builtin_amdgcn_mfma_f32_16x16x32_bf16(a1, qf1, s[j], 0, 0, 0);
    }

    // softmax scale + mask + coalesced float4 weight stores + bf16 pack
    u32 wpk[8];
#pragma unroll
    for (int j = 0; j < 4; ++j) {
      const int4 mm = *(const int4*)(Mrow + kb + 16 * j + 4 * g);
      float w0 = mm.x ? __expf(s[j][0] * 0.125f) * inv : 0.f;
      float w1 = mm.y ? __expf(s[j][1] * 0.125f) * inv : 0.f;
      float w2 = mm.z ? __expf(s[j][2] * 0.125f) * inv : 0.f;
      float w3 = mm.w ? __expf(s[j][3] * 0.125f) * inv : 0.f;
      f32x4 wv = {w0, w1, w2, w3};
      *(f32x4*)(wrow + kb + 16 * j + 4 * g) = wv;
      wpk[2 * j]     = (u32)f2bs(w0) | ((u32)f2bs(w1) << 16);
      wpk[2 * j + 1] = (u32)f2bs(w2) | ((u32)f2bs(w3) << 16);
    }

    // PV: D[d][q] = V^T * W ; B = W straight from registers (no LDS trip)
#pragma unroll
    for (int h = 0; h < 2; ++h) {
      u32x4 wbu = {wpk[4 * h], wpk[4 * h + 1], wpk[4 * h + 2], wpk[4 * h + 3]};
      bf16x8 wb = __builtin_bit_cast(bf16x8, wbu);
#pragma unroll
      for (int dt = 0; dt < 4; ++dt) {
        u32x2 vlo = *(const u32x2*)&Vt[cur][16 * dt + c][32 * h + 4 * g];
        u32x2 vhi = *(const u32x2*)&Vt[cur][16 * dt + c][32 * h + 16 + 4 * g];
        u32x4 vau = {vlo.x, vlo.y, vhi.x, vhi.y};
        bf16x8 va = __builtin_bit_cast(bf16x8, vau);
        acc[dt] = __builtin_amdgcn_mfma_f32_16x16x32_bf16(va, wb, acc[dt], 0, 0, 0);
      }
    }

    if (it + 1 < NIT) { writeK((it + 1) & 1); writeV((it + 1) & 1); }
    __syncthreads();
  }

  // ctx store: lane (g,c) holds ctx[q0w+c][16dt+4g+r] -> float4 stores
  float* crow = ctx + (bq + q0w + c) * ND;
#pragma unroll
  for (int dt = 0; dt < 4; ++dt)
    *(f32x4*)(crow + 16 * dt + 4 * g) = acc[dt];
}

extern "C" void kernel_launch(void* const* d_in, const int* in_sizes, int n_in,
                              void* d_out, int out_size, void* d_ws, size_t ws_size,
                              hipStream_t stream) {
  const float* Q = (const float*)d_in[0];
  const float* K = (const float*)d_in[1];
  const float* V = (const float*)d_in[2];
  const int*   M = (const int*)d_in[3];
  float* ctx = (float*)d_out;                         // [B,S,D]
  float* wts = (float*)d_out + (size_t)NB * NS * ND;  // [B,S,S]

  dim3 grid(NB * (NS / 64));
  dim3 block(256);
  hipLaunchKernelGGL(DotProductAttention_22436909154804_kernel, grid, block, 0, stream,
                     Q, K, V, M, ctx, wts);
}